// Round 10
// baseline (352.158 us; speedup 1.0000x reference)
//
#include <hip/hip_runtime.h>

#define INVB  2.0f      // 1/beta
#define TOL   0.1f
#define EPS   1e-8f
#define NITER 50
#define NP    4         // blocks per graph

// ---------------------------------------------------------------------------
// P=4 blocks/graph, 1024 threads each (512 blocks = 2/CU co-resident; VGPR
// must stay <= 64 for the graph-local spin sync's residency guarantee).
// Log-space implicit T:  T_k = exp(LD_k[n] + LS_k[m] - k*INVB*C[n,m]).
// Exp-factored single-scan iteration (C rows register-resident, 2-deep
// prefetch):
//   F  = exp(-INVB*c), G = exp(LD_{k+1} + LS_{k+1}[m] - k*INVB*c)
//   T_{k+1} = G*F ; T_k = G*r_row*rs[m]     (r_row = b_k/mu, rs = a/mu)
//   bterm   = G*F^2*sig[m]                  (sig = mu/a)
//   a-part  = bterm*rs[m]*(mu/b_{k+1})      (zero-exp, registers only)
// OUTPUTS IN A DEDICATED FINAL SWEEP (r7/r8: in-scan output streams triple
// HBM traffic). IDENTITY BLOCK MAPPING (r9 post-mortem: the XCD swizzle
// inflated FETCH 248->412 MB and WRITE 294->598 MB — the bid&7==XCD dispatch
// assumption is wrong on this chip; remap destroyed L2/MALL retention).
// ---------------------------------------------------------------------------

__device__ __forceinline__ float wsum(float v) {
    #pragma unroll
    for (int o = 1; o < 64; o <<= 1) v += __shfl_xor(v, o, 64);
    return v;   // all lanes hold the total
}

__device__ __forceinline__ void group_arrive(unsigned* flagp) {
    __hip_atomic_fetch_add(flagp, 1u, __ATOMIC_RELEASE, __HIP_MEMORY_SCOPE_AGENT);
}
__device__ __forceinline__ void group_wait(unsigned* flagp, unsigned target) {
    long sp = 0;
    while (__hip_atomic_load(flagp, __ATOMIC_RELAXED, __HIP_MEMORY_SCOPE_AGENT)
               < target && sp < (1L << 24)) {
        __builtin_amdgcn_s_sleep(2); ++sp;
    }
    (void)__hip_atomic_load(flagp, __ATOMIC_ACQUIRE, __HIP_MEMORY_SCOPE_AGENT);
}

// ------------- pre-kernel: zero control words + mask dtype detect -----------
__global__ void k_zero(unsigned* ctrl, int ctrlwords, int* mode,
                       const unsigned* mraw, int nwords) {
    const int t = threadIdx.x;
    for (int i = t; i < ctrlwords; i += 1024) ctrl[i] = 0u;
    __shared__ int sF, sB;
    if (t == 0) { sF = 0; sB = 0; }
    __syncthreads();
    int f = 0, b = 0;
    for (int i = t; i < nwords; i += 1024) {
        unsigned w = mraw[i];
        if (w == 0x3f800000u) f = 1;
        else if (w > 1u)      b = 1;
    }
    if (f) atomicOr(&sF, 1);
    if (b) atomicOr(&sB, 1);
    __syncthreads();
    if (t == 0) *mode = sF ? 2 : (sB ? 1 : 0);
}

// ============================ main kernel ===================================
__global__ __launch_bounds__(1024, 8) void k_ipot4(
    const float* __restrict__ C, const void* __restrict__ mraw,
    int bs, int N,
    unsigned* err_u, unsigned* flags, float* dpart, const int* mode_p,
    float* apart, float* outD, float* outT, float* outC)
{
    const int g    = blockIdx.x >> 2;          // graph (identity mapping)
    const int p    = blockIdx.x & 3;           // sub-block
    const int t    = threadIdx.x;
    const int lane = t & 63;
    const int wv   = t >> 6;                   // 0..15
    const int NR   = N >> 2;                   // own rows (128)
    const int r0   = p * NR;
    const int rpw  = NR >> 4;                  // rows per wave (8)
    const float NEG = -__builtin_inff();
    unsigned* flagp = &flags[g * 16];

    __shared__ __align__(16) float m01[512];     // col mask 0/1
    __shared__ __align__(16) float ls_s[512];    // LS (log) current
    __shared__ __align__(16) float sig_s[512];   // mu/a (sigma')
    __shared__ __align__(16) float rs_s[512];    // a/mu (1/sigma')
    __shared__ float ld_own[128], ldp_own[128], ldr_own[128];
    __shared__ __align__(16) float ap_ws[16][512];
    __shared__ float red_s[16];
    __shared__ float muv_s, cnt_s, errg_s;
    __shared__ unsigned errbits_s;

    // ---- init ----
    {
        const int mode = *mode_p;
        if (t < N) {
            const int idx = g * N + t;
            bool mv;
            if (mode == 1)      mv = ((const unsigned char*)mraw)[idx] != 0;
            else if (mode == 2) mv = ((const float*)mraw)[idx] != 0.0f;
            else                mv = ((const int*)mraw)[idx] != 0;
            m01[t]  = mv ? 1.f : 0.f;
            ls_s[t] = mv ? 0.f : NEG;
            sig_s[t] = 0.f; rs_s[t] = 0.f;
        }
        __syncthreads();
        if (t < N) {
            float v = wsum(m01[t]);
            if (lane == 0) red_s[wv] = v;
        }
        __syncthreads();
        if (t == 0) {
            float cnt = 0.f;
            for (int i = 0; i < (N >> 6); ++i) cnt += red_s[i];
            cnt_s = cnt;                 // >= 1 by setup
            muv_s = 1.0f / cnt;
        }
        __syncthreads();
    }
    const float muv = muv_s, cnt = cnt_s;
    unsigned rnd = 0;

    const float* wbase = C + ((size_t)g * N + r0 + wv * rpw) * N + lane * 4;
    const int mb0 = lane * 4, mb1 = 256 + lane * 4;

    // ---- pass 0: b0 + a0 partials (no stores -> C stays cache-clean) ----
    {
        float4 ca = *(const float4*)(wbase);
        float4 cb = *(const float4*)(wbase + 256);
        float4 da = *(const float4*)(wbase + (size_t)N);
        float4 db = *(const float4*)(wbase + (size_t)N + 256);
        const float4 m40 = *(const float4*)(&m01[mb0]);
        const float4 m41 = *(const float4*)(&m01[mb1]);
        float4 fa0 = {0,0,0,0}, fa1 = {0,0,0,0};
        for (int j = 0; j < rpw; ++j) {
            const int jn = (j + 2 < rpw) ? (j + 2) : (rpw - 1);
            const float4 na = *(const float4*)(wbase + (size_t)jn * N);
            const float4 nb = *(const float4*)(wbase + (size_t)jn * N + 256);
            const int lo = wv * rpw + j;
            const bool valid = m01[r0 + lo] != 0.f;
            float4 bt0, bt1;
            bt0.x = m40.x * __expf(-INVB * ca.x);
            bt0.y = m40.y * __expf(-INVB * ca.y);
            bt0.z = m40.z * __expf(-INVB * ca.z);
            bt0.w = m40.w * __expf(-INVB * ca.w);
            bt1.x = m41.x * __expf(-INVB * cb.x);
            bt1.y = m41.y * __expf(-INVB * cb.y);
            bt1.z = m41.z * __expf(-INVB * cb.z);
            bt1.w = m41.w * __expf(-INVB * cb.w);
            float bacc = bt0.x + bt0.y + bt0.z + bt0.w
                       + bt1.x + bt1.y + bt1.z + bt1.w;
            bacc = wsum(bacc);           // b0 = muv * bacc
            float q, ld1, ldr;
            if (valid) { q = 1.0f / bacc; ld1 = __logf(q); ldr = bacc; }
            else       { q = 0.f;         ld1 = NEG;       ldr = 0.f;  }
            if (lane == 0) { ld_own[lo] = ld1; ldr_own[lo] = ldr; }
            fa0.x += q * bt0.x; fa0.y += q * bt0.y;
            fa0.z += q * bt0.z; fa0.w += q * bt0.w;
            fa1.x += q * bt1.x; fa1.y += q * bt1.y;
            fa1.z += q * bt1.z; fa1.w += q * bt1.w;
            ca = da; cb = db; da = na; db = nb;
        }
        *(float4*)&ap_ws[wv][mb0] = fa0;
        *(float4*)&ap_ws[wv][mb1] = fa1;
    }
    __syncthreads();
    if (t < N) {
        float av = 0.f;
        #pragma unroll
        for (int w = 0; w < 16; ++w) av += ap_ws[w][t];
        apart[((size_t)(g * NP + p)) * N + t] = av;
    }
    __syncthreads();
    ++rnd;
    if (t == 0) { group_arrive(flagp); group_wait(flagp, NP * rnd); }
    __syncthreads();
    if (t < N && m01[t] != 0.f) {
        float av = 0.f;
        #pragma unroll
        for (int q2 = 0; q2 < NP; ++q2)
            av += apart[((size_t)(g * NP + q2)) * N + t];
        const float sg = muv / av;       // av > 0 for valid cols
        ls_s[t] += __logf(sg);
        sig_s[t] = sg;
        rs_s[t]  = av * cnt;
    }
    __syncthreads();

    // ---- iterations: ONE register-resident C scan each; NO output stores ----
    int kf = NITER;
    for (int it = 0; it < NITER; ++it) {
        const float s1 = (float)it * INVB;
        if (t == 0) errbits_s = 0u;
        __syncthreads();
        {
            float4 ca = *(const float4*)(wbase);
            float4 cb = *(const float4*)(wbase + 256);
            float4 da = *(const float4*)(wbase + (size_t)N);
            float4 db = *(const float4*)(wbase + (size_t)N + 256);
            float4 fa0 = {0,0,0,0}, fa1 = {0,0,0,0};
            float errmax = 0.f;
            for (int j = 0; j < rpw; ++j) {
                const int jn = (j + 2 < rpw) ? (j + 2) : (rpw - 1);
                const float4 na = *(const float4*)(wbase + (size_t)jn * N);
                const float4 nb = *(const float4*)(wbase + (size_t)jn * N + 256);
                const int lo = wv * rpw + j;
                const bool valid = m01[r0 + lo] != 0.f;
                const float ldn = ld_own[lo];
                const float ldr = ldr_own[lo];
                const float4 ln0 = *(const float4*)(&ls_s[mb0]);
                const float4 ln1 = *(const float4*)(&ls_s[mb1]);
                const float4 sg0 = *(const float4*)(&sig_s[mb0]);
                const float4 sg1 = *(const float4*)(&sig_s[mb1]);
                const float4 rs0 = *(const float4*)(&rs_s[mb0]);
                const float4 rs1 = *(const float4*)(&rs_s[mb1]);
                float eacc = 0.f, bacc = 0.f;
                float4 bt0, bt1;
                #define IPOT_E(cc, LN, SG, RS, BT)                          \
                  { float F  = __expf(-INVB * (cc));                        \
                    float G  = __expf(ldn + (LN) - s1 * (cc));              \
                    float tn = G * F;                                       \
                    float to = G * ldr * (RS);                              \
                    eacc += fabsf(tn - to);                                 \
                    (BT) = tn * F * (SG);                                   \
                    bacc += (BT); }
                IPOT_E(ca.x, ln0.x, sg0.x, rs0.x, bt0.x)
                IPOT_E(ca.y, ln0.y, sg0.y, rs0.y, bt0.y)
                IPOT_E(ca.z, ln0.z, sg0.z, rs0.z, bt0.z)
                IPOT_E(ca.w, ln0.w, sg0.w, rs0.w, bt0.w)
                IPOT_E(cb.x, ln1.x, sg1.x, rs1.x, bt1.x)
                IPOT_E(cb.y, ln1.y, sg1.y, rs1.y, bt1.y)
                IPOT_E(cb.z, ln1.z, sg1.z, rs1.z, bt1.z)
                IPOT_E(cb.w, ln1.w, sg1.w, rs1.w, bt1.w)
                #undef IPOT_E
                bacc = wsum(bacc);
                eacc = wsum(eacc);
                errmax = fmaxf(errmax, eacc);
                float q, ldn2, ldrn;
                if (valid) { q = muv / bacc; ldn2 = ldn + __logf(q); ldrn = bacc * cnt; }
                else       { q = 0.f;        ldn2 = NEG;             ldrn = 0.f;       }
                if (lane == 0) {
                    ldp_own[lo] = ldn;       // LD_{it+1} == LD_kf on break
                    ld_own[lo]  = ldn2;      // LD_{it+2}
                    ldr_own[lo] = ldrn;
                }
                // a_{k+1} partials: zero-exp, registers only
                fa0.x += q * bt0.x * rs0.x; fa0.y += q * bt0.y * rs0.y;
                fa0.z += q * bt0.z * rs0.z; fa0.w += q * bt0.w * rs0.w;
                fa1.x += q * bt1.x * rs1.x; fa1.y += q * bt1.y * rs1.y;
                fa1.z += q * bt1.z * rs1.z; fa1.w += q * bt1.w * rs1.w;
                ca = da; cb = db; da = na; db = nb;
            }
            if (lane == 0) atomicMax(&errbits_s, __float_as_uint(errmax));
            *(float4*)&ap_ws[wv][mb0] = fa0;
            *(float4*)&ap_ws[wv][mb1] = fa1;
        }
        __syncthreads();
        if (t < N) {
            float av = 0.f;
            #pragma unroll
            for (int w = 0; w < 16; ++w) av += ap_ws[w][t];
            apart[((size_t)(g * NP + p)) * N + t] = av;
        }
        if (t == 0) atomicMax(&err_u[g * 64 + it], errbits_s);
        __syncthreads();
        ++rnd;
        if (t == 0) {
            group_arrive(flagp); group_wait(flagp, NP * rnd);
            errg_s = __uint_as_float(err_u[g * 64 + it]);
        }
        __syncthreads();
        if (errg_s < TOL) { kf = it + 1; break; }
        if (it == NITER - 1) { kf = NITER; break; }
        if (t < N && m01[t] != 0.f) {
            float av = 0.f;
            #pragma unroll
            for (int q2 = 0; q2 < NP; ++q2)
                av += apart[((size_t)(g * NP + q2)) * N + t];
            const float sg = muv / av;
            ls_s[t] += __logf(sg);
            sig_s[t] = sg;
            rs_s[t]  = av * cnt;
        }
        __syncthreads();
    }

    // ---- final sweep: T out + C copy (plain stores) + distance dot ----
    float dacc = 0.f;
    {
        const float sF = (float)kf * INVB;
        float4 ca = *(const float4*)(wbase);
        float4 cb = *(const float4*)(wbase + 256);
        float4 da = *(const float4*)(wbase + (size_t)N);
        float4 db = *(const float4*)(wbase + (size_t)N + 256);
        for (int j = 0; j < rpw; ++j) {
            const int jn = (j + 2 < rpw) ? (j + 2) : (rpw - 1);
            const float4 na = *(const float4*)(wbase + (size_t)jn * N);
            const float4 nb = *(const float4*)(wbase + (size_t)jn * N + 256);
            const int lo = wv * rpw + j;
            const int gr = g * N + r0 + lo;
            const float ldv = ldp_own[lo];     // LD_kf
            const float4 ln0 = *(const float4*)(&ls_s[mb0]);
            const float4 ln1 = *(const float4*)(&ls_s[mb1]);
            float4 t0, t1;
            t0.x = __expf(ldv + ln0.x - sF * ca.x);
            t0.y = __expf(ldv + ln0.y - sF * ca.y);
            t0.z = __expf(ldv + ln0.z - sF * ca.z);
            t0.w = __expf(ldv + ln0.w - sF * ca.w);
            t1.x = __expf(ldv + ln1.x - sF * cb.x);
            t1.y = __expf(ldv + ln1.y - sF * cb.y);
            t1.z = __expf(ldv + ln1.z - sF * cb.z);
            t1.w = __expf(ldv + ln1.w - sF * cb.w);
            dacc += t0.x * ca.x + t0.y * ca.y + t0.z * ca.z + t0.w * ca.w;
            dacc += t1.x * cb.x + t1.y * cb.y + t1.z * cb.z + t1.w * cb.w;
            const size_t grN = (size_t)gr * N;
            *(float4*)(outT + grN + mb0) = t0;
            *(float4*)(outT + grN + mb1) = t1;
            *(float4*)(outC + grN + mb0) = ca;
            *(float4*)(outC + grN + mb1) = cb;
            ca = da; cb = db; da = na; db = nb;
        }
    }
    dacc = wsum(dacc);
    if (lane == 0) red_s[wv] = dacc;
    __syncthreads();
    ++rnd;
    if (t == 0) {
        float d = 0.f;
        #pragma unroll
        for (int w = 0; w < 16; ++w) d += red_s[w];
        dpart[g * NP + p] = d;
        group_arrive(flagp);
        if (p == 0) {
            group_wait(flagp, NP * rnd);
            float dt = 0.f;
            #pragma unroll
            for (int q2 = 0; q2 < NP; ++q2) dt += dpart[g * NP + q2];
            outD[g] = dt;
        }
    }
}

// ---------------------------------------------------------------------------
extern "C" void kernel_launch(void* const* d_in, const int* in_sizes, int n_in,
                              void* d_out, int out_size, void* d_ws, size_t ws_size,
                              hipStream_t stream) {
    const float* C    = (const float*)d_in[0];
    const void*  mask = d_in[4];
    const int R  = in_sizes[4];           // bs*N
    const int N  = in_sizes[0] / R;       // 512
    const int bs = R / N;                 // 128

    unsigned* wsu   = (unsigned*)d_ws;
    unsigned* err_u = wsu;                          // bs*64
    unsigned* flags = wsu + (size_t)bs * 64;        // bs*16
    float*    dpart = (float*)(flags + (size_t)bs * 16);   // bs*NP
    int*      mode  = (int*)(dpart + (size_t)bs * NP);     // 1
    const int ctrlwords = bs * 64 + bs * 16 + bs * NP + 1;
    float*    apart = (float*)(wsu + ((ctrlwords + 255) & ~255)); // bs*NP*N

    float* outD = (float*)d_out;
    float* outT = outD + bs;
    float* outC = outT + (size_t)bs * N * N;

    k_zero<<<1, 1024, 0, stream>>>(wsu, ctrlwords, mode,
                                   (const unsigned*)mask, R / 4);
    k_ipot4<<<bs * NP, 1024, 0, stream>>>(C, mask, bs, N,
                                          err_u, flags, dpart, mode,
                                          apart, outD, outT, outC);
}

// Round 11
// 237.199 us; speedup vs baseline: 1.4847x; 1.4847x over previous
//
#include <hip/hip_runtime.h>

#define INVB  2.0f      // 1/beta
#define TOL   0.1f
#define EPS   1e-8f
#define NITER 50
#define NP    4         // blocks per graph

// ---------------------------------------------------------------------------
// P=4 blocks per graph, 1024 threads each (512 blocks = 2/CU co-resident;
// VGPR must stay <= 64 for the graph-local spin sync's residency guarantee).
// Block p owns rows [p*128, p*128+128) of its graph. Log-space implicit T:
//   T_k = exp(LD_k[n] + LS_k[m] - k*INVB*C[n,m]),  -inf masks invalid.
// ONE C-pass per iteration: per own row, scan1 computes err_k + b_{k+1};
// then LD_{k+2} = LD_{k+1} + log(mu/b_{k+1}) is known immediately, and scan2
// (L1-hot re-read of the same row) accumulates the NEXT col sums.
// This two-scan form is deliberately register-lean: r6/r9/r10's single-scan
// "register-resident" variant exceeded the 64-VGPR budget, spilled to
// scratch, and inflated HBM traffic by ~470 MB (FETCH 248->415, WRITE
// 294->600). Do NOT persist per-element products across the wsum chains.
// Per iteration: 1 graph-local 4-block sync (a-partials + err exchange).
// ---------------------------------------------------------------------------

__device__ __forceinline__ float wsum(float v) {
    #pragma unroll
    for (int o = 1; o < 64; o <<= 1) v += __shfl_xor(v, o, 64);
    return v;   // all lanes hold the total
}

__device__ __forceinline__ void group_arrive(unsigned* flagp) {
    __hip_atomic_fetch_add(flagp, 1u, __ATOMIC_RELEASE, __HIP_MEMORY_SCOPE_AGENT);
}
__device__ __forceinline__ void group_wait(unsigned* flagp, unsigned target) {
    long sp = 0;
    while (__hip_atomic_load(flagp, __ATOMIC_RELAXED, __HIP_MEMORY_SCOPE_AGENT)
               < target && sp < (1L << 24)) {
        __builtin_amdgcn_s_sleep(2); ++sp;
    }
    (void)__hip_atomic_load(flagp, __ATOMIC_ACQUIRE, __HIP_MEMORY_SCOPE_AGENT);
}

// ------------- pre-kernel: zero control words + mask dtype detect -----------
__global__ void k_zero(unsigned* ctrl, int ctrlwords, int* mode,
                       const unsigned* mraw, int nwords) {
    const int t = threadIdx.x;
    for (int i = t; i < ctrlwords; i += 1024) ctrl[i] = 0u;
    __shared__ int sF, sB;
    if (t == 0) { sF = 0; sB = 0; }
    __syncthreads();
    int f = 0, b = 0;
    for (int i = t; i < nwords; i += 1024) {
        unsigned w = mraw[i];
        if (w == 0x3f800000u) f = 1;
        else if (w > 1u)      b = 1;
    }
    if (f) atomicOr(&sF, 1);
    if (b) atomicOr(&sB, 1);
    __syncthreads();
    if (t == 0) *mode = sF ? 2 : (sB ? 1 : 0);
}

// ============================ main kernel ===================================
__global__ __launch_bounds__(1024, 8) void k_ipot4(
    const float* __restrict__ C, const void* __restrict__ mraw,
    int bs, int N,
    unsigned* err_u, unsigned* flags, float* dpart, const int* mode_p,
    float* apart, float* outD, float* outT, float* outC)
{
    const int g    = blockIdx.x >> 2;          // graph
    const int p    = blockIdx.x & 3;           // sub-block in graph
    const int t    = threadIdx.x;
    const int lane = t & 63;
    const int wv   = t >> 6;                   // 0..15
    const int NR   = N >> 2;                   // own rows (128)
    const int r0   = p * NR;
    const int rpw  = NR >> 4;                  // rows per wave (8)
    const float NEG = -__builtin_inff();
    unsigned* flagp = &flags[g * 16];

    __shared__ __align__(16) float ls_s[512];    // LS current
    __shared__ __align__(16) float lsp_s[512];   // LS previous
    __shared__ __align__(16) float lsig_s[512];  // log sigma current
    __shared__ __align__(16) float m01[512];     // col mask 0/1
    __shared__ float ld_own[128], ldp_own[128];  // own-row LD cur/prev
    __shared__ __align__(16) float ap_ws[16][512]; // per-wave col partials
    __shared__ float red_s[16];
    __shared__ float muv_s, lmu_s, errg_s;
    __shared__ unsigned errbits_s;

    // ---- init: mask row, count, scalings ----
    {
        const int mode = *mode_p;
        if (t < N) {
            const int idx = g * N + t;
            bool mv;
            if (mode == 1)      mv = ((const unsigned char*)mraw)[idx] != 0;
            else if (mode == 2) mv = ((const float*)mraw)[idx] != 0.0f;
            else                mv = ((const int*)mraw)[idx] != 0;
            m01[t] = mv ? 1.f : 0.f;
            const float z = mv ? 0.f : NEG;
            ls_s[t] = z; lsp_s[t] = z;
        }
        __syncthreads();
        if (t < N) {
            float v = wsum(m01[t]);
            if (lane == 0) red_s[wv] = v;
        }
        __syncthreads();
        if (t == 0) {
            float cnt = 0.f;
            for (int i = 0; i < (N >> 6); ++i) cnt += red_s[i];
            muv_s = 1.0f / cnt;                 // cnt >= 1 by setup
            lmu_s = __logf(muv_s);
        }
        __syncthreads();
        if (t < N) lsig_s[t] = (m01[t] != 0.f) ? lmu_s : NEG;
        if (t < NR) {
            const float z = (m01[r0 + t] != 0.f) ? 0.f : NEG;
            ld_own[t] = z; ldp_own[t] = z;
        }
        __syncthreads();
    }
    const float muv = muv_s, lmu = lmu_s;
    unsigned rnd = 0;

    // ---- pass 0: b0 (own rows) + a0 partials ----
    {
        float4 fa[2] = {{0,0,0,0},{0,0,0,0}};
        for (int j = 0; j < rpw; ++j) {
            const int lo = wv * rpw + j;
            const int n  = r0 + lo;
            const bool valid = m01[n] != 0.f;
            const float* crow = C + ((size_t)g * N + n) * N;
            float bacc = 0.f;
            if (valid) {
                #pragma unroll
                for (int mg = 0; mg < 2; ++mg) {
                    const int mb = mg * 256 + lane * 4;
                    float4 c4 = *(const float4*)(crow + mb);
                    float4 m4 = *(const float4*)(&m01[mb]);
                    bacc += m4.x * __expf(lmu - INVB * c4.x);
                    bacc += m4.y * __expf(lmu - INVB * c4.y);
                    bacc += m4.z * __expf(lmu - INVB * c4.z);
                    bacc += m4.w * __expf(lmu - INVB * c4.w);
                }
            }
            bacc = wsum(bacc);
            const float ldn1 = valid ? __logf(muv / bacc) : NEG;  // LD_1
            if (lane == 0) ld_own[lo] = ldn1;
            if (valid) {
                #pragma unroll
                for (int mg = 0; mg < 2; ++mg) {
                    const int mb = mg * 256 + lane * 4;
                    float4 c4 = *(const float4*)(crow + mb);     // L1-hot
                    float4 l4 = *(const float4*)(&ls_s[mb]);
                    fa[mg].x += __expf(ldn1 + l4.x - INVB * c4.x);
                    fa[mg].y += __expf(ldn1 + l4.y - INVB * c4.y);
                    fa[mg].z += __expf(ldn1 + l4.z - INVB * c4.z);
                    fa[mg].w += __expf(ldn1 + l4.w - INVB * c4.w);
                }
            }
        }
        *(float4*)&ap_ws[wv][lane * 4]       = fa[0];
        *(float4*)&ap_ws[wv][256 + lane * 4] = fa[1];
        __syncthreads();
        if (t < N) {
            float av = 0.f;
            #pragma unroll
            for (int w = 0; w < 16; ++w) av += ap_ws[w][t];
            apart[((size_t)(g * NP + p)) * N + t] = av;
        }
        __syncthreads();
        ++rnd;
        if (t == 0) { group_arrive(flagp); group_wait(flagp, NP * rnd); }
        __syncthreads();
        if (t < N && m01[t] != 0.f) {          // LS_1 / lsig_1 (all identical)
            float av = 0.f;
            #pragma unroll
            for (int q = 0; q < NP; ++q) av += apart[((size_t)(g * NP + q)) * N + t];
            const float lsg = __logf(muv / av);
            lsp_s[t] = ls_s[t]; ls_s[t] += lsg; lsig_s[t] = lsg;
        }
        __syncthreads();
    }

    // ---- iterations: one C-pass each (two-scan, register-lean) ----
    int kf = NITER;
    for (int it = 0; it < NITER; ++it) {
        const float s1 = (float)it * INVB;
        const float s2 = s1 + INVB;
        const float s3 = s2 + INVB;
        if (t == 0) errbits_s = 0u;
        float4 fa[2] = {{0,0,0,0},{0,0,0,0}};
        float errmax = 0.f;
        __syncthreads();

        for (int j = 0; j < rpw; ++j) {
            const int lo = wv * rpw + j;
            const int n  = r0 + lo;
            const bool valid = m01[n] != 0.f;
            const float ldn = ld_own[lo], ldo = ldp_own[lo];
            const float* crow = C + ((size_t)g * N + n) * N;
            float eacc = 0.f, bacc = 0.f;
            if (valid) {
                #pragma unroll
                for (int mg = 0; mg < 2; ++mg) {
                    const int mb = mg * 256 + lane * 4;
                    float4 c4  = *(const float4*)(crow + mb);
                    float4 ln4 = *(const float4*)(&ls_s[mb]);
                    float4 lo4 = *(const float4*)(&lsp_s[mb]);
                    float4 lg4 = *(const float4*)(&lsig_s[mb]);
                    float tn, to;
                    tn = __expf(ldn + ln4.x - s2 * c4.x);
                    to = __expf(ldo + lo4.x - s1 * c4.x);
                    eacc += fabsf(tn - to);
                    bacc += __expf(ldn + ln4.x + lg4.x - s3 * c4.x);
                    tn = __expf(ldn + ln4.y - s2 * c4.y);
                    to = __expf(ldo + lo4.y - s1 * c4.y);
                    eacc += fabsf(tn - to);
                    bacc += __expf(ldn + ln4.y + lg4.y - s3 * c4.y);
                    tn = __expf(ldn + ln4.z - s2 * c4.z);
                    to = __expf(ldo + lo4.z - s1 * c4.z);
                    eacc += fabsf(tn - to);
                    bacc += __expf(ldn + ln4.z + lg4.z - s3 * c4.z);
                    tn = __expf(ldn + ln4.w - s2 * c4.w);
                    to = __expf(ldo + lo4.w - s1 * c4.w);
                    eacc += fabsf(tn - to);
                    bacc += __expf(ldn + ln4.w + lg4.w - s3 * c4.w);
                }
            }
            bacc = wsum(bacc);
            eacc = wsum(eacc);
            errmax = fmaxf(errmax, eacc);
            const float ldn2 = valid ? (ldn + __logf(muv / bacc)) : NEG; // LD_{k+2}
            if (lane == 0) { ldp_own[lo] = ldn; ld_own[lo] = ldn2; }
            if (valid) {
                #pragma unroll
                for (int mg = 0; mg < 2; ++mg) {
                    const int mb = mg * 256 + lane * 4;
                    float4 c4 = *(const float4*)(crow + mb);     // L1-hot
                    float4 l4 = *(const float4*)(&ls_s[mb]);
                    fa[mg].x += __expf(ldn2 + l4.x - s3 * c4.x);
                    fa[mg].y += __expf(ldn2 + l4.y - s3 * c4.y);
                    fa[mg].z += __expf(ldn2 + l4.z - s3 * c4.z);
                    fa[mg].w += __expf(ldn2 + l4.w - s3 * c4.w);
                }
            }
        }
        if (lane == 0) atomicMax(&errbits_s, __float_as_uint(errmax));
        *(float4*)&ap_ws[wv][lane * 4]       = fa[0];
        *(float4*)&ap_ws[wv][256 + lane * 4] = fa[1];
        __syncthreads();
        if (t < N) {
            float av = 0.f;
            #pragma unroll
            for (int w = 0; w < 16; ++w) av += ap_ws[w][t];
            apart[((size_t)(g * NP + p)) * N + t] = av;
        }
        if (t == 0) atomicMax(&err_u[g * 64 + it], errbits_s);
        __syncthreads();
        ++rnd;
        if (t == 0) {
            group_arrive(flagp); group_wait(flagp, NP * rnd);
            errg_s = __uint_as_float(err_u[g * 64 + it]);
        }
        __syncthreads();
        if (errg_s < TOL) { kf = it + 1; break; }
        if (it == NITER - 1) { kf = NITER; break; }
        if (t < N && m01[t] != 0.f) {          // LS_{k+2}, lsig_{k+2}
            float av = 0.f;
            #pragma unroll
            for (int q = 0; q < NP; ++q) av += apart[((size_t)(g * NP + q)) * N + t];
            const float lsg = __logf(muv / av);
            lsp_s[t] = ls_s[t]; ls_s[t] += lsg; lsig_s[t] = lsg;
        }
        __syncthreads();
    }

    // ---- final: T out + C copy + per-thread distance dot (own rows) ----
    float dacc = 0.f;
    {
        const float sF = (float)kf * INVB;
        for (int j = 0; j < rpw; ++j) {
            const int lo = wv * rpw + j;
            const int gr = g * N + r0 + lo;
            const float ldv = ldp_own[lo];     // LD_kf (ld_own holds kf+1)
            const float* crow = C + (size_t)gr * N;
            float* trow = outT + (size_t)gr * N;
            float* orow = outC + (size_t)gr * N;
            #pragma unroll
            for (int mg = 0; mg < 2; ++mg) {
                const int mb = mg * 256 + lane * 4;
                float4 c4 = *(const float4*)(crow + mb);
                float4 l4 = *(const float4*)(&ls_s[mb]);
                float4 t4;
                t4.x = __expf(ldv + l4.x - sF * c4.x);
                t4.y = __expf(ldv + l4.y - sF * c4.y);
                t4.z = __expf(ldv + l4.z - sF * c4.z);
                t4.w = __expf(ldv + l4.w - sF * c4.w);
                dacc += t4.x * c4.x + t4.y * c4.y + t4.z * c4.z + t4.w * c4.w;
                *(float4*)(trow + mb) = t4;
                *(float4*)(orow + mb) = c4;
            }
        }
    }
    // block-reduce distance partial
    dacc = wsum(dacc);
    if (lane == 0) red_s[wv] = dacc;
    __syncthreads();
    ++rnd;
    if (t == 0) {
        float d = 0.f;
        #pragma unroll
        for (int w = 0; w < 16; ++w) d += red_s[w];
        dpart[g * NP + p] = d;
        group_arrive(flagp);
        if (p == 0) {
            group_wait(flagp, NP * rnd);
            float dt = 0.f;
            #pragma unroll
            for (int q = 0; q < NP; ++q) dt += dpart[g * NP + q];
            outD[g] = dt;
        }
    }
}

// ---------------------------------------------------------------------------
extern "C" void kernel_launch(void* const* d_in, const int* in_sizes, int n_in,
                              void* d_out, int out_size, void* d_ws, size_t ws_size,
                              hipStream_t stream) {
    const float* C    = (const float*)d_in[0];
    const void*  mask = d_in[4];
    const int R  = in_sizes[4];           // bs*N
    const int N  = in_sizes[0] / R;       // 512
    const int bs = R / N;                 // 128

    unsigned* wsu   = (unsigned*)d_ws;
    unsigned* err_u = wsu;                          // bs*64
    unsigned* flags = wsu + (size_t)bs * 64;        // bs*16
    float*    dpart = (float*)(flags + (size_t)bs * 16);   // bs*NP
    int*      mode  = (int*)(dpart + (size_t)bs * NP);     // 1
    const int ctrlwords = bs * 64 + bs * 16 + bs * NP + 1;
    float*    apart = (float*)(wsu + ((ctrlwords + 255) & ~255)); // bs*NP*N

    float* outD = (float*)d_out;
    float* outT = outD + bs;
    float* outC = outT + (size_t)bs * N * N;

    k_zero<<<1, 1024, 0, stream>>>(wsu, ctrlwords, mode,
                                   (const unsigned*)mask, R / 4);
    k_ipot4<<<bs * NP, 1024, 0, stream>>>(C, mask, bs, N,
                                          err_u, flags, dpart, mode,
                                          apart, outD, outT, outC);
}